// Round 19
// baseline (1327.684 us; speedup 1.0000x reference)
//
#include <hip/hip_runtime.h>

// Semi-CRF log-partition. B=4, T=512, L=96, W=63.
// v19 = v11 structure + 2-BATCH INTERLEAVING (batches are independent chains;
// R = E^w is batch-independent -> shared registers). Each group g handles
// batches {2g, 2g+1}: finalizer waves do role(A) then role(B) per iteration,
// so the fixed per-iteration cost (flag latency, skew ~0.9us) amortizes over
// 2 time-steps and each stage's waits overlap the other batch's compute.
// Helpers run ONE TARGET AHEAD (d2/d3 produce slot(t+1) from ring[t-1]/[t-2]).
// Relays: d=4..63, 4-way target split (t mod 4), serve both batches/iter.
// Handoffs: 8B relaxed agent atomics (axp NaN sentinel, chain tag in low 8
// mantissa bits of v); LDS flags relaxed + lgkmcnt(0). 512 thr, VGPR=128.

#define Tn 512
#define Ln 96
#define HL 48
#define LSQ (Ln * Ln)
#define Wn 63
#define KCH 8
#define NROLE 61  // per group: 1 finalizer + 60 relay roles (4 units each)
#define NEGINF (-1e30f)
#define SENT 0x7FC00000u

#define AGENT __HIP_MEMORY_SCOPE_AGENT
#define WG __HIP_MEMORY_SCOPE_WORKGROUP
#define RLX __ATOMIC_RELAXED
#define LDSF() asm volatile("s_waitcnt lgkmcnt(0)" ::: "memory")
#define CBAR() asm volatile("" ::: "memory")
#define SIDX(b, i, t) ((((size_t)(b) * Tn + (i)) * Tn + (t)) * Ln)

typedef unsigned long long u64;
typedef unsigned int u32;

__device__ __forceinline__ float wsumred(float v) {
#pragma unroll
  for (int m = 32; m >= 1; m >>= 1) v += __shfl_xor(v, m, 64);
  return v;
}
__device__ __forceinline__ u64 pack2(float lo, float hi) {
  return (u64)__float_as_uint(lo) | ((u64)__float_as_uint(hi) << 32);
}
__device__ __forceinline__ float wavemax48(float v) {
  int x;
  x = __builtin_amdgcn_update_dpp(__float_as_int(v), __float_as_int(v), 0xB1,
                                  0xF, 0xF, false);
  v = fmaxf(v, __int_as_float(x));
  x = __builtin_amdgcn_update_dpp(__float_as_int(v), __float_as_int(v), 0x4E,
                                  0xF, 0xF, false);
  v = fmaxf(v, __int_as_float(x));
  x = __builtin_amdgcn_update_dpp(__float_as_int(v), __float_as_int(v), 0x141,
                                  0xF, 0xF, false);
  v = fmaxf(v, __int_as_float(x));
  x = __builtin_amdgcn_update_dpp(__float_as_int(v), __float_as_int(v), 0x140,
                                  0xF, 0xF, false);
  v = fmaxf(v, __int_as_float(x));
  float r0 = __int_as_float(__builtin_amdgcn_readlane(__float_as_int(v), 0));
  float r1 = __int_as_float(__builtin_amdgcn_readlane(__float_as_int(v), 16));
  float r2 = __int_as_float(__builtin_amdgcn_readlane(__float_as_int(v), 32));
  float r3 = __int_as_float(__builtin_amdgcn_readlane(__float_as_int(v), 48));
  return fmaxf(fmaxf(r0, r1), fmaxf(r2, r3));
}
__device__ __forceinline__ float comb(float Slo, float Shi, float C0, float C1,
                                      float wseg) {
  const float Cm = fmaxf(C0, C1);
  return Cm + wseg + __logf(__expf(C0 - Cm) * Slo + __expf(C1 - Cm) * Shi);
}

// f32 matvec: 24 ds_read_b128
#define MV1(SRC, RR, SLO, SHI)                                       \
  float SLO, SHI;                                                    \
  {                                                                  \
    const float4* A4 = (const float4*)(SRC);                         \
    float a0 = 0, a1 = 0, a2 = 0, a3 = 0;                            \
    _Pragma("unroll") for (int q = 0; q < 12; ++q) {                 \
      float4 a = A4[q];                                              \
      a0 = fmaf(a.x, RR[4 * q + 0], a0);                             \
      a1 = fmaf(a.y, RR[4 * q + 1], a1);                             \
      a2 = fmaf(a.z, RR[4 * q + 2], a2);                             \
      a3 = fmaf(a.w, RR[4 * q + 3], a3);                             \
    }                                                                \
    SLO = (a0 + a1) + (a2 + a3);                                     \
    float b0 = 0, b1 = 0, b2 = 0, b3 = 0;                            \
    _Pragma("unroll") for (int q = 12; q < 24; ++q) {                \
      float4 a = A4[q];                                              \
      b0 = fmaf(a.x, RR[4 * q + 0], b0);                             \
      b1 = fmaf(a.y, RR[4 * q + 1], b1);                             \
      b2 = fmaf(a.z, RR[4 * q + 2], b2);                             \
      b3 = fmaf(a.w, RR[4 * q + 3], b3);                             \
    }                                                                \
    SHI = (b0 + b1) + (b2 + b3);                                     \
  }

__global__ void init_ws(u64* ws) {
  const size_t n1 = (size_t)4 * Tn * Ln;
  const size_t n = n1 * 9;  // axp + 8 chains
  for (size_t i = (size_t)blockIdx.x * blockDim.x + threadIdx.x; i < n;
       i += (size_t)gridDim.x * blockDim.x)
    ws[i] = (i < n1) ? (((u64)SENT) << 32) : 0ull;
}

__global__ __launch_bounds__(512, 1) void semicrf(
    const float* __restrict__ seg, const float* __restrict__ tr,
    float* __restrict__ out, u64* axp, u64* acc) {
  const int g = blockIdx.x / NROLE;   // batch group: batches 2g, 2g+1
  const int role = blockIdx.x % NROLE;
  const int tid = threadIdx.x;
  const int bA = 2 * g, bB = 2 * g + 1;

  __shared__ __align__(16) float E[LSQ];              // exp(trans) 36 KB
  __shared__ __align__(16) float AlbR[2][8][Ln];      // alpha rings (A,B)
  __shared__ float CRng[2][8][2];                     // per-half C rings
  __shared__ __align__(16) float slotC2[2][4][Ln];    // d2 contributions
  __shared__ __align__(16) float slotC3[2][4][Ln];    // d3 contributions
  __shared__ float RESTm[2][4][Ln];                   // chains+z merge (m)
  __shared__ float RESTv[2][4][Ln];                   // chains+z merge (v)
  __shared__ __align__(16) float Alb_s[4][2][2][Ln];  // relay staging
  __shared__ float CstS[4][2][2][2];                  // [pair][X][buf][half]
  __shared__ float redbuf[2][2];                      // [X][half]
  __shared__ int seqA[2][2], sp2[2][2], sp3[2][2], rq[2][2], rfl[2];
  __shared__ int stg[4][2];

  if (tid < 4) {
    seqA[tid >> 1][tid & 1] = -1;
    sp2[tid >> 1][tid & 1] = -1;
    sp3[tid >> 1][tid & 1] = -1;
    rq[tid >> 1][tid & 1] = -1;
  }
  if (tid < 2) rfl[tid] = -1;
  if (tid < 8) stg[tid >> 1][tid & 1] = -1;
  for (int i = tid; i < LSQ; i += 512) E[i] = __expf(tr[i]);
  __syncthreads();  // the only block-wide barrier

  if (role != 0) {
    // ==== relay unit: pu=(role-1)*4+pair -> d=4+pu/4, split m4=pu%4 =========
    const int pair = tid >> 7;
    const int tp = tid & 127;
    const int wv = tp >> 6;
    const int rl = tp & 63;
    const bool act = rl < HL;
    const int lab = wv * HL + (act ? rl : HL - 1);
    const int pu = (role - 1) * 4 + pair;  // 0..239
    const int d = 4 + (pu >> 2);           // 4..63
    const int m4 = pu & 3;
    const int j = d & 7;
    u64* chA = acc + (size_t)(j * 4 + bA) * Tn * Ln;
    u64* chB = acc + (size_t)(j * 4 + bB) * Tn * Ln;
    const u64* axA = axp + (size_t)bA * Tn * Ln;
    const u64* axB = axp + (size_t)bB * Tn * Ln;
    float R[Ln];
#pragma unroll
    for (int lp = 0; lp < Ln; ++lp) R[lp] = E[lp * Ln + lab];
    int wc = 1;
    const bool aHead = (d + KCH > Wn);
    const int t0 = d + ((m4 - (d & 3)) + 4) % 4;
    int bufi = 0;

    for (int t = t0; t < Tn; t += 4) {
      const int s = t - d;
      const int w = (t <= Wn) ? (s + 1) : (64 - d);
      while (w > wc) {
        ++wc;
#pragma unroll
        for (int lp = 0; lp < Ln; ++lp) R[lp] *= E[lp * Ln + lab];
      }
      const float segA = seg[SIDX(bA, s + 1, t) + lab];
      const float segB = seg[SIDX(bB, s + 1, t) + lab];
      const size_t tIdx = (size_t)t * Ln + lab;
      const bool head = aHead || (s < KCH);
      u64 uaA = 0, uaB = 0;
      if (!head) {
        uaA = __hip_atomic_load(&chA[tIdx], RLX, AGENT);
        uaB = __hip_atomic_load(&chB[tIdx], RLX, AGENT);
      }
      u64 upA = __hip_atomic_load(&axA[(size_t)s * Ln + lab], RLX, AGENT);
      u64 upB = __hip_atomic_load(&axB[(size_t)s * Ln + lab], RLX, AGENT);
      while ((u32)(upA >> 32) == SENT)
        upA = __hip_atomic_load(&axA[(size_t)s * Ln + lab], RLX, AGENT);
      while ((u32)(upB >> 32) == SENT)
        upB = __hip_atomic_load(&axB[(size_t)s * Ln + lab], RLX, AGENT);

      if (act) {
        Alb_s[pair][0][bufi][lab] = __uint_as_float((u32)upA);
        Alb_s[pair][1][bufi][lab] = __uint_as_float((u32)upB);
      }
      if (rl == 0) {
        CstS[pair][0][bufi][wv] = __uint_as_float((u32)(upA >> 32));
        CstS[pair][1][bufi][wv] = __uint_as_float((u32)(upB >> 32));
      }
      LDSF();
      __hip_atomic_store(&stg[pair][wv], t, RLX, WG);
      while (__hip_atomic_load(&stg[pair][wv ^ 1], RLX, WG) < t) {}
      CBAR();
      const float CA0 = CstS[pair][0][bufi][0], CA1 = CstS[pair][0][bufi][1];
      const float CB0 = CstS[pair][1][bufi][0], CB1 = CstS[pair][1][bufi][1];
      MV1(Alb_s[pair][0][bufi], R, SloA, ShiA)
      MV1(Alb_s[pair][1][bufi], R, SloB, ShiB)
      const float cA = comb(SloA, ShiA, CA0, CA1, (float)w * segA);
      const float cB = comb(SloB, ShiB, CB0, CB1, (float)w * segB);
      bufi ^= 1;

#define CHAINOUT(UA, CC, CH)                                              \
  {                                                                       \
    float m, v;                                                           \
    if (head) {                                                           \
      m = CC;                                                             \
      v = 1.f;                                                            \
    } else {                                                              \
      while (((UA >> 32) & 0xFFu) != (u32)(d + KCH))                      \
        UA = __hip_atomic_load(&CH[tIdx], RLX, AGENT);                    \
      const float pm = __uint_as_float((u32)UA);                          \
      const float pv = __uint_as_float(((u32)(UA >> 32)) & ~0xFFu);       \
      const float nm = fmaxf(pm, CC);                                     \
      v = pv * __expf(pm - nm) + __expf(CC - nm);                         \
      m = nm;                                                             \
    }                                                                     \
    if (act) {                                                            \
      const u32 vb = (__float_as_uint(v) & ~0xFFu) | (u32)d;              \
      __hip_atomic_store(&CH[tIdx],                                       \
                         (u64)__float_as_uint(m) | ((u64)vb << 32), RLX,  \
                         AGENT);                                          \
    }                                                                     \
  }
      CHAINOUT(uaA, cA, chA)
      CHAINOUT(uaB, cB, chB)
    }
    return;
  }

  // ======================= finalizer (2 batches) ===========================
  const int w6 = tid >> 6;
  const int l = tid & 63;
  const bool act = l < HL;
  const int h = w6 & 1;
  const int lab = h * HL + (act ? l : HL - 1);
  const float bos = tr[LSQ + lab];

  if (w6 < 2) {
    // ---- CORE wave h: both batches per iteration --------------------------
    float R1[Ln];
#pragma unroll
    for (int lp = 0; lp < Ln; ++lp) R1[lp] = E[lp * Ln + lab];
    int w1c = 1;
#pragma unroll
    for (int X = 0; X < 2; ++X) {  // seed t=0
      const int bb = 2 * g + X;
      const float a0 = __expf(seg[SIDX(bb, 0, 0) + lab] + bos);
      const float Cw = wavemax48(act ? a0 : NEGINF);
      const float ax0 = __expf(a0 - Cw);
      if (act)
        __hip_atomic_store(&axp[(size_t)bb * Tn * Ln + lab], pack2(ax0, Cw),
                           RLX, AGENT);
      if (act) AlbR[X][0][lab] = ax0;
      if (l == 0) CRng[X][0][h] = Cw;
      LDSF();
      __hip_atomic_store(&seqA[X][h], 0, RLX, WG);
    }
    float qd0[2], qd1[2];
#pragma unroll
    for (int X = 0; X < 2; ++X) {
      qd0[X] = seg[SIDX(2 * g + X, 1, 1) + lab];
      qd1[X] = seg[SIDX(2 * g + X, 2, 2) + lab];
    }

    for (int t = 1; t < Tn; ++t) {
      const int w1 = (t <= Wn) ? t : Wn;
      if (w1 > w1c) {
        w1c = w1;
#pragma unroll
        for (int lp = 0; lp < Ln; ++lp) R1[lp] *= E[lp * Ln + lab];
      }
#pragma unroll
      for (int X = 0; X < 2; ++X) {
        const int bb = 2 * g + X;
        const float s1 = qd0[X];
        qd0[X] = qd1[X];
        if (t + 2 < Tn) qd1[X] = seg[SIDX(bb, t + 2, t + 2) + lab];
        while (__hip_atomic_load(&seqA[X][h ^ 1], RLX, WG) < t - 1) {}
        CBAR();
        const float C0 = CRng[X][(t - 1) & 7][0], C1 = CRng[X][(t - 1) & 7][1];
        MV1(AlbR[X][(t - 1) & 7], R1, Slo, Shi)
        const float c1 = comb(Slo, Shi, C0, C1, (float)w1 * s1);
        float c2 = NEGINF, c3 = NEGINF;
        if (t >= 2) {
          while (__hip_atomic_load(&sp2[X][h], RLX, WG) < t) {}
          CBAR();
          c2 = slotC2[X][t & 3][lab];
        }
        if (t >= 3) {
          while (__hip_atomic_load(&sp3[X][h], RLX, WG) < t) {}
          CBAR();
          c3 = slotC3[X][t & 3][lab];
        }
        while (__hip_atomic_load(&rq[X][h], RLX, WG) < t) {}
        CBAR();
        const float mr = RESTm[X][t & 3][lab], vr = RESTv[X][t & 3][lab];
        const float M = fmaxf(fmaxf(c1, c2), fmaxf(c3, mr));
        const float vs = __expf(c1 - M) + __expf(c2 - M) + __expf(c3 - M) +
                         vr * __expf(mr - M);
        const float alpha = M + __logf(vs);
        const float Cw = wavemax48(act ? alpha : NEGINF);
        const float axn = __expf(alpha - Cw);
        if (act)
          __hip_atomic_store(&axp[((size_t)bb * Tn + t) * Ln + lab],
                             pack2(axn, Cw), RLX, AGENT);
        if (act) AlbR[X][t & 7][lab] = axn;
        if (l == 0) CRng[X][t & 7][h] = Cw;
        LDSF();
        __hip_atomic_store(&seqA[X][h], t, RLX, WG);
        if (t == Tn - 1) {
          const float sm = wsumred(act ? axn : 0.f);
          if (l == 0) redbuf[X][h] = Cw + __logf(sm);
        }
      }
    }
    LDSF();
    __hip_atomic_store(&rfl[h], 1, RLX, WG);
    if (h == 0 && l == 0) {
      while (__hip_atomic_load(&rfl[1], RLX, WG) < 1) {}
      CBAR();
#pragma unroll
      for (int X = 0; X < 2; ++X) {
        const float G0 = redbuf[X][0], G1 = redbuf[X][1];
        const float Mx = fmaxf(G0, G1);
        out[2 * g + X] = Mx + __logf(__expf(G0 - Mx) + __expf(G1 - Mx));
      }
    }
    return;
  }

  if (w6 < 4) {
    // ---- d2 wave (half h): produce slot2(tt=ti+1) from ring[ti-1] ---------
    float R2[Ln];
#pragma unroll
    for (int lp = 0; lp < Ln; ++lp) R2[lp] = E[lp * Ln + lab];
    int wc = 1;
    float q0[2], q1[2];
#pragma unroll
    for (int X = 0; X < 2; ++X) {
      q0[X] = seg[SIDX(2 * g + X, 1, 2) + lab];  // tt=2
      q1[X] = seg[SIDX(2 * g + X, 2, 3) + lab];  // tt=3
    }
    for (int ti = 1; ti < Tn - 1; ++ti) {
      const int tt = ti + 1;
      const int w = (tt <= Wn) ? (tt - 1) : 62;
      while (w > wc) {
        ++wc;
#pragma unroll
        for (int lp = 0; lp < Ln; ++lp) R2[lp] *= E[lp * Ln + lab];
      }
#pragma unroll
      for (int X = 0; X < 2; ++X) {
        const float sv = q0[X];
        q0[X] = q1[X];
        if (tt + 2 < Tn) q1[X] = seg[SIDX(2 * g + X, tt + 1, tt + 2) + lab];
        while (__hip_atomic_load(&seqA[X][0], RLX, WG) < ti - 1 ||
               __hip_atomic_load(&seqA[X][1], RLX, WG) < ti - 1) {}
        CBAR();
        const float C0 = CRng[X][(ti - 1) & 7][0],
                    C1 = CRng[X][(ti - 1) & 7][1];
        MV1(AlbR[X][(ti - 1) & 7], R2, Slo, Shi)
        const float c = comb(Slo, Shi, C0, C1, (float)w * sv);
        if (act) slotC2[X][tt & 3][lab] = c;
        LDSF();
        __hip_atomic_store(&sp2[X][h], tt, RLX, WG);
      }
    }
    return;
  }

  if (w6 < 6) {
    // ---- d3 wave (half h): produce slot3(tt=ti+1) from ring[ti-2] ---------
    float R3[Ln];
#pragma unroll
    for (int lp = 0; lp < Ln; ++lp) R3[lp] = E[lp * Ln + lab];
    int wc = 1;
    float q0[2], q1[2];
#pragma unroll
    for (int X = 0; X < 2; ++X) {
      q0[X] = seg[SIDX(2 * g + X, 1, 3) + lab];  // tt=3
      q1[X] = seg[SIDX(2 * g + X, 2, 4) + lab];  // tt=4
    }
    for (int ti = 2; ti < Tn - 1; ++ti) {
      const int tt = ti + 1;
      const int w = (tt <= Wn) ? (tt - 2) : 61;
      while (w > wc) {
        ++wc;
#pragma unroll
        for (int lp = 0; lp < Ln; ++lp) R3[lp] *= E[lp * Ln + lab];
      }
#pragma unroll
      for (int X = 0; X < 2; ++X) {
        const float sv = q0[X];
        q0[X] = q1[X];
        if (tt + 2 < Tn) q1[X] = seg[SIDX(2 * g + X, tt, tt + 2) + lab];
        while (__hip_atomic_load(&seqA[X][0], RLX, WG) < ti - 2 ||
               __hip_atomic_load(&seqA[X][1], RLX, WG) < ti - 2) {}
        CBAR();
        const float C0 = CRng[X][(ti - 2) & 7][0],
                    C1 = CRng[X][(ti - 2) & 7][1];
        MV1(AlbR[X][(ti - 2) & 7], R3, Slo, Shi)
        const float c = comb(Slo, Shi, C0, C1, (float)w * sv);
        if (act) slotC3[X][tt & 3][lab] = c;
        LDSF();
        __hip_atomic_store(&sp3[X][h], tt, RLX, WG);
      }
    }
    return;
  }

  {
    // ---- REST wave (half h): chains (d>=4) + z for tt=ti+1 ----------------
    const int endd[8] = {8, 9, 10, 11, 4, 5, 6, 7};  // chain end per residue
    u64 u[2][8];
    float zq0[2], zq1[2];
#pragma unroll
    for (int X = 0; X < 2; ++X) {
#pragma unroll
      for (int jj = 0; jj < 8; ++jj) u[X][jj] = 0;
      zq0[X] = seg[SIDX(2 * g + X, 0, 2) + lab];  // z(2)
      zq1[X] = seg[SIDX(2 * g + X, 0, 3) + lab];  // z(3)
      // seed REST(1) = z(1)
      const float zv = 2.f * (seg[SIDX(2 * g + X, 0, 1) + lab] + bos);
      if (act) {
        RESTm[X][1][lab] = zv;
        RESTv[X][1][lab] = 1.f;
      }
      LDSF();
      __hip_atomic_store(&rq[X][h], 1, RLX, WG);
    }

    for (int ti = 1; ti < Tn - 1; ++ti) {
      const int tt = ti + 1;
#pragma unroll
      for (int X = 0; X < 2; ++X) {
        const int bb = 2 * g + X;
        const float zv = (tt <= Wn) ? (float)(tt + 1) * (zq0[X] + bos) : NEGINF;
        zq0[X] = zq1[X];
        if (tt + 2 <= Wn) zq1[X] = seg[SIDX(bb, 0, tt + 2) + lab];
        float M = zv;
        float em[8], ev[8];
#pragma unroll
        for (int jj = 0; jj < 8; ++jj) {
          if (tt >= endd[jj]) {
            const size_t aIdx = (((size_t)jj * 4 + bb) * Tn + tt) * Ln + lab;
            while (((u[X][jj] >> 32) & 0xFFu) != (u32)endd[jj])
              u[X][jj] = __hip_atomic_load(&acc[aIdx], RLX, AGENT);
            em[jj] = __uint_as_float((u32)u[X][jj]);
            ev[jj] = __uint_as_float(((u32)(u[X][jj] >> 32)) & ~0xFFu);
            M = fmaxf(M, em[jj]);
          } else {
            em[jj] = NEGINF;
            ev[jj] = 0.f;
          }
        }
        float vs = __expf(zv - M);
#pragma unroll
        for (int jj = 0; jj < 8; ++jj) vs += ev[jj] * __expf(em[jj] - M);
        if (act) {
          RESTm[X][tt & 3][lab] = M;
          RESTv[X][tt & 3][lab] = vs;
        }
        LDSF();
        __hip_atomic_store(&rq[X][h], tt, RLX, WG);
        // depth-1 prefetch for tt+1
        if (tt + 1 < Tn) {
#pragma unroll
          for (int jj = 0; jj < 8; ++jj)
            if (tt + 1 >= endd[jj])
              u[X][jj] = __hip_atomic_load(
                  &acc[(((size_t)jj * 4 + bb) * Tn + (tt + 1)) * Ln + lab],
                  RLX, AGENT);
        }
      }
    }
    return;
  }
}

extern "C" void kernel_launch(void* const* d_in, const int* in_sizes, int n_in,
                              void* d_out, int out_size, void* d_ws,
                              size_t ws_size, hipStream_t stream) {
  const float* seg = (const float*)d_in[0];  // (4,512,512,96) f32
  const float* tr = (const float*)d_in[1];   // (97,96) f32
  float* out = (float*)d_out;                // (4,) f32

  u64* axp = (u64*)d_ws;                 // [4][512][96]
  u64* acc = axp + (size_t)4 * Tn * Ln;  // [8][4][512][96]

  hipLaunchKernelGGL(init_ws, dim3(2048), dim3(256), 0, stream, (u64*)d_ws);
  hipLaunchKernelGGL(semicrf, dim3(2 * NROLE), dim3(512), 0, stream, seg, tr,
                     out, axp, acc);
}